// Round 2
// baseline (822.152 us; speedup 1.0000x reference)
//
#include <hip/hip_runtime.h>
#include <hip/hip_bf16.h>

#define T_SEQ 4096
#define HID   2048
#define NH    16
#define NKV   4
#define HD    128
#define QKV_N 3072
#define SCALE 0.08838834764831845f
#define MASK_NEG -3.0e4f

typedef unsigned short u16;
typedef __bf16 bf16x8 __attribute__((ext_vector_type(8)));
typedef float floatx4 __attribute__((ext_vector_type(4)));

__device__ __forceinline__ float b2f(u16 u) {
  union { unsigned int i; float f; } x; x.i = ((unsigned int)u) << 16; return x.f;
}
__device__ __forceinline__ u16 f2b(float f) {
  union { float f; unsigned int i; } x; x.f = f;
  unsigned int i = x.i;
  unsigned int r = (i + 0x7FFFu + ((i >> 16) & 1u)) >> 16;
  return (u16)r;
}
__device__ __forceinline__ void gload_lds16(const u16* g, u16* lds) {
  __builtin_amdgcn_global_load_lds(
      (const __attribute__((address_space(1))) unsigned int*)g,
      (__attribute__((address_space(3))) unsigned int*)lds, 16, 0, 0);
}

// Stage a 128x32 f32 tile (rows base0.., k offset k0..) into LDS as bf16 with
// layout s[32*r + c] = M[base0+r][k0+c]. 256 threads, 2 chunks of 8 each.
__device__ __forceinline__ void stage_f32(const float* __restrict__ G, int ld,
                                          int base0, int k0, u16* s, int tid) {
#pragma unroll
  for (int q = 0; q < 2; q++) {
    int v = tid * 2 + q;
    const float* g = G + (size_t)(base0 + (v >> 2)) * ld + k0 + (v & 3) * 8;
    float4 f0 = *(const float4*)g;
    float4 f1 = *(const float4*)(g + 4);
    union { u16 h[8]; uint4 u; } r;
    r.h[0] = f2b(f0.x); r.h[1] = f2b(f0.y); r.h[2] = f2b(f0.z); r.h[3] = f2b(f0.w);
    r.h[4] = f2b(f1.x); r.h[5] = f2b(f1.y); r.h[6] = f2b(f1.z); r.h[7] = f2b(f1.w);
    *(uint4*)(s + v * 8) = r.u;
  }
}

// C[M,N] = A[M,K] * B[N,K]^T. AF/BF: operand is f32 (else bf16). CF: store f32
// (else bf16). bf16 compute, f32 accumulate. 128x128 tile, BK=32.
template <int AF, int BF, int CF>
__global__ __launch_bounds__(256) void gemm_bt(const void* __restrict__ Av, int lda,
                                               const void* __restrict__ Bv, int ldb,
                                               void* __restrict__ Cv, int ldc, int K) {
  __shared__ __align__(16) u16 sA[128 * 32];
  __shared__ __align__(16) u16 sB[128 * 32];
  const int tid = threadIdx.x;
  const int wave = tid >> 6, lane = tid & 63;
  const int row0 = blockIdx.y * 128, col0 = blockIdx.x * 128;
  const int wm = (wave >> 1) * 64, wn = (wave & 1) * 64;
  const int frow = lane & 15, fk = (lane >> 4) * 8;

  floatx4 acc[4][4];
#pragma unroll
  for (int i = 0; i < 4; i++)
#pragma unroll
    for (int j = 0; j < 4; j++) acc[i][j] = (floatx4){0.f, 0.f, 0.f, 0.f};

  const int c0 = wave * 2;
  const int v0 = c0 * 64 + lane;
  const int v1 = v0 + 64;

  for (int k0 = 0; k0 < K; k0 += 32) {
    if (AF) {
      stage_f32((const float*)Av, lda, row0, k0, sA, tid);
    } else {
      const u16* A = (const u16*)Av;
      gload_lds16(A + (size_t)(row0 + (v0 >> 2)) * lda + (v0 & 3) * 8 + k0, sA + c0 * 512);
      gload_lds16(A + (size_t)(row0 + (v1 >> 2)) * lda + (v1 & 3) * 8 + k0, sA + c0 * 512 + 512);
    }
    if (BF) {
      stage_f32((const float*)Bv, ldb, col0, k0, sB, tid);
    } else {
      const u16* B = (const u16*)Bv;
      gload_lds16(B + (size_t)(col0 + (v0 >> 2)) * ldb + (v0 & 3) * 8 + k0, sB + c0 * 512);
      gload_lds16(B + (size_t)(col0 + (v1 >> 2)) * ldb + (v1 & 3) * 8 + k0, sB + c0 * 512 + 512);
    }
    __syncthreads();
    bf16x8 af[4], bfv[4];
#pragma unroll
    for (int i = 0; i < 4; i++) {
      af[i]  = *(const bf16x8*)(sA + (wm + i * 16 + frow) * 32 + fk);
      bfv[i] = *(const bf16x8*)(sB + (wn + i * 16 + frow) * 32 + fk);
    }
#pragma unroll
    for (int i = 0; i < 4; i++)
#pragma unroll
      for (int j = 0; j < 4; j++)
        acc[i][j] = __builtin_amdgcn_mfma_f32_16x16x32_bf16(af[i], bfv[j], acc[i][j], 0, 0, 0);
    __syncthreads();
  }
  const int crow = (lane >> 4) * 4, ccol = lane & 15;
#pragma unroll
  for (int i = 0; i < 4; i++)
#pragma unroll
    for (int j = 0; j < 4; j++)
#pragma unroll
      for (int r = 0; r < 4; r++) {
        int rr = row0 + wm + i * 16 + crow + r;
        int cc = col0 + wn + j * 16 + ccol;
        if (CF) ((float*)Cv)[(size_t)rr * ldc + cc] = acc[i][j][r];
        else    ((u16*)Cv)[(size_t)rr * ldc + cc] = f2b(acc[i][j][r]);
      }
}

// Per-token RoPE (q,k heads) then RMSNorm over full q(2048)/k(512), in place on
// the bf16 qkv buffer. Norm weights are f32.
__global__ __launch_bounds__(256) void rope_norm(const int* __restrict__ pos_arr,
                                                 u16* __restrict__ qkv,
                                                 const float* __restrict__ qnw,
                                                 const float* __restrict__ knw) {
  const int t = blockIdx.x;
  const int tid = threadIdx.x;
  const int lane = tid & 63, wave = tid >> 6;
  u16* row = qkv + (size_t)t * QKV_N;
  const float pos = (float)pos_arr[t];

  float qv[8];
  float ssq = 0.f;
#pragma unroll
  for (int i = 0; i < 8; i++) {
    int e = tid * 8 + i;
    int r = e & 127, ih = e & 63;
    float invf = __expf(-(float)ih * 0.14391156831212787f); // ln(10000)/64
    float ang = pos * invf;
    float s, c;
    sincosf(ang, &s, &c);
    float val;
    if (r < 64) val = b2f(row[e]) * c - b2f(row[e + 64]) * s;
    else        val = b2f(row[e]) * c + b2f(row[e - 64]) * s;
    qv[i] = val;
    ssq += val * val;
  }
  float kv[2];
  float ssk = 0.f;
  const u16* krow = row + HID;
#pragma unroll
  for (int i = 0; i < 2; i++) {
    int e = tid * 2 + i;
    int r = e & 127, ih = e & 63;
    float invf = __expf(-(float)ih * 0.14391156831212787f);
    float ang = pos * invf;
    float s, c;
    sincosf(ang, &s, &c);
    float val;
    if (r < 64) val = b2f(krow[e]) * c - b2f(krow[e + 64]) * s;
    else        val = b2f(krow[e]) * c + b2f(krow[e - 64]) * s;
    kv[i] = val;
    ssk += val * val;
  }
#pragma unroll
  for (int off = 1; off < 64; off <<= 1) {
    ssq += __shfl_xor(ssq, off);
    ssk += __shfl_xor(ssk, off);
  }
  __shared__ float rq[4], rk[4];
  if (lane == 0) { rq[wave] = ssq; rk[wave] = ssk; }
  __syncthreads();  // also orders all in-place reads before the writes below
  float sq = rq[0] + rq[1] + rq[2] + rq[3];
  float sk = rk[0] + rk[1] + rk[2] + rk[3];
  float qsc = rsqrtf(sq * (1.0f / 2048.0f) + 1e-5f);
  float ksc = rsqrtf(sk * (1.0f / 512.0f) + 1e-5f);
#pragma unroll
  for (int i = 0; i < 8; i++) {
    int e = tid * 8 + i;
    row[e] = f2b(qv[i] * qsc * qnw[e]);
  }
#pragma unroll
  for (int i = 0; i < 2; i++) {
    int e = tid * 2 + i;
    row[HID + e] = f2b(kv[i] * ksc * knw[e]);
  }
}

// vt[h][d][t] = qkv[t][2560 + h*128 + d]
__global__ __launch_bounds__(256) void transpose_v(const u16* __restrict__ qkv,
                                                   u16* __restrict__ vt) {
  __shared__ __align__(16) u16 tile[64][136];
  const int tid = threadIdx.x;
  const int h = blockIdx.y;
  const int t0 = blockIdx.x * 64;
#pragma unroll
  for (int p = 0; p < 4; p++) {
    int v = p * 256 + tid;
    int r = v >> 4, c = v & 15;
    const u16* g = qkv + (size_t)(t0 + r) * QKV_N + (HID + NKV * HD) + h * HD + c * 8;
    *(uint4*)(&tile[r][c * 8]) = *(const uint4*)g;
  }
  __syncthreads();
#pragma unroll
  for (int p = 0; p < 4; p++) {
    int v = p * 256 + tid;
    int d = v >> 3, c8 = v & 7;
    union { u16 s[8]; uint4 q; } tmp;
#pragma unroll
    for (int i = 0; i < 8; i++) tmp.s[i] = tile[c8 * 8 + i][d];
    u16* g = vt + ((size_t)h * HD + d) * T_SEQ + t0 + c8 * 8;
    *(uint4*)g = tmp.q;
  }
}

// Flash attention: block = (64 q rows, 1 head), 4 waves (16 q rows each).
__global__ __launch_bounds__(256) void attn_kernel(u16* __restrict__ qkv,
                                                   const u16* __restrict__ vt) {
  __shared__ __align__(16) u16 sKt[32 * 128]; // [kv][d]
  __shared__ __align__(16) u16 sVt[128 * 32]; // [d][kv]
  __shared__ __align__(16) u16 sP[4 * 512];   // per-wave [16 q][32 kv]
  const int tid = threadIdx.x;
  const int wave = tid >> 6, lane = tid & 63;
  const int h = blockIdx.y, kvh = h >> 2;
  const int q0 = blockIdx.x * 64;
  const int qw = q0 + wave * 16;
  const int frow = lane & 15, fq = lane >> 4;
  const int fk = fq * 8;

  bf16x8 qf[4];
  {
    const u16* qrow = qkv + (size_t)(qw + frow) * QKV_N + h * HD + fk;
#pragma unroll
    for (int kt = 0; kt < 4; kt++) qf[kt] = *(const bf16x8*)(qrow + kt * 32);
  }
  floatx4 o[8];
#pragma unroll
  for (int dt = 0; dt < 8; dt++) o[dt] = (floatx4){0.f, 0.f, 0.f, 0.f};
  float m_run[4] = {MASK_NEG, MASK_NEG, MASK_NEG, MASK_NEG};
  float l_run[4] = {0.f, 0.f, 0.f, 0.f};

  const int kv_end = q0 + 64;
  for (int kv0 = 0; kv0 < kv_end; kv0 += 32) {
    {
      const int c = wave * 2;
      int v = c * 64 + lane;
      const u16* gk = qkv + (size_t)(kv0 + (v >> 4)) * QKV_N + HID + kvh * HD + (v & 15) * 8;
      gload_lds16(gk, sKt + c * 512);
      const u16* gv = vt + ((size_t)kvh * HD + (v >> 2)) * T_SEQ + kv0 + (v & 3) * 8;
      gload_lds16(gv, sVt + c * 512);
      v += 64;
      const u16* gk1 = qkv + (size_t)(kv0 + (v >> 4)) * QKV_N + HID + kvh * HD + (v & 15) * 8;
      gload_lds16(gk1, sKt + c * 512 + 512);
      const u16* gv1 = vt + ((size_t)kvh * HD + (v >> 2)) * T_SEQ + kv0 + (v & 3) * 8;
      gload_lds16(gv1, sVt + c * 512 + 512);
    }
    __syncthreads();
    if (kv0 <= qw + 15) {
      floatx4 s[2];
#pragma unroll
      for (int nt = 0; nt < 2; nt++) {
        floatx4 a = (floatx4){0.f, 0.f, 0.f, 0.f};
#pragma unroll
        for (int kt = 0; kt < 4; kt++) {
          bf16x8 kf = *(const bf16x8*)(sKt + (nt * 16 + frow) * 128 + kt * 32 + fk);
          a = __builtin_amdgcn_mfma_f32_16x16x32_bf16(qf[kt], kf, a, 0, 0, 0);
        }
        s[nt] = a;
      }
      float mloc[4], alpha[4], psum[4];
#pragma unroll
      for (int r = 0; r < 4; r++) {
        int qg = qw + fq * 4 + r;
#pragma unroll
        for (int nt = 0; nt < 2; nt++) {
          int kg = kv0 + nt * 16 + frow;
          float val = s[nt][r] * SCALE;
          s[nt][r] = (kg > qg) ? MASK_NEG : val;
        }
        mloc[r] = fmaxf(s[0][r], s[1][r]);
      }
#pragma unroll
      for (int off = 1; off < 16; off <<= 1)
#pragma unroll
        for (int r = 0; r < 4; r++)
          mloc[r] = fmaxf(mloc[r], __shfl_xor(mloc[r], off));
#pragma unroll
      for (int r = 0; r < 4; r++) {
        float mn = fmaxf(m_run[r], mloc[r]);
        alpha[r] = __expf(m_run[r] - mn);
        m_run[r] = mn;
        float p0 = __expf(s[0][r] - mn);
        float p1 = __expf(s[1][r] - mn);
        s[0][r] = p0;
        s[1][r] = p1;
        psum[r] = p0 + p1;
      }
#pragma unroll
      for (int off = 1; off < 16; off <<= 1)
#pragma unroll
        for (int r = 0; r < 4; r++)
          psum[r] += __shfl_xor(psum[r], off);
#pragma unroll
      for (int r = 0; r < 4; r++) l_run[r] = l_run[r] * alpha[r] + psum[r];
#pragma unroll
      for (int dt = 0; dt < 8; dt++)
#pragma unroll
        for (int r = 0; r < 4; r++) o[dt][r] *= alpha[r];
      // P (C-layout) -> LDS -> A-operand layout (bf16), per-wave buffer
      u16* pw = sP + wave * 512;
#pragma unroll
      for (int nt = 0; nt < 2; nt++)
#pragma unroll
        for (int r = 0; r < 4; r++)
          pw[(fq * 4 + r) * 32 + nt * 16 + frow] = f2b(s[nt][r]);
      asm volatile("s_waitcnt lgkmcnt(0)" ::: "memory");
      bf16x8 pa = *(const bf16x8*)(pw + frow * 32 + fk);
#pragma unroll
      for (int dt = 0; dt < 8; dt++) {
        bf16x8 vf = *(const bf16x8*)(sVt + (dt * 16 + frow) * 32 + fk);
        o[dt] = __builtin_amdgcn_mfma_f32_16x16x32_bf16(pa, vf, o[dt], 0, 0, 0);
      }
    }
    __syncthreads();
  }
  float inv[4];
#pragma unroll
  for (int r = 0; r < 4; r++) inv[r] = 1.0f / fmaxf(l_run[r], 1e-20f);
#pragma unroll
  for (int dt = 0; dt < 8; dt++)
#pragma unroll
    for (int r = 0; r < 4; r++) {
      int t = qw + fq * 4 + r;
      int col = h * HD + dt * 16 + frow;
      qkv[(size_t)t * QKV_N + col] = f2b(o[dt][r] * inv[r]);
    }
}

extern "C" void kernel_launch(void* const* d_in, const int* in_sizes, int n_in,
                              void* d_out, int out_size, void* d_ws, size_t ws_size,
                              hipStream_t stream) {
  const int* positions = (const int*)d_in[0];
  const float* hidden = (const float*)d_in[1];
  const float* w_qkv = (const float*)d_in[2];
  const float* w_o = (const float*)d_in[3];
  const float* qnw = (const float*)d_in[4];
  const float* knw = (const float*)d_in[5];
  float* out = (float*)d_out;

  u16* qkv = (u16*)d_ws;                  // [4096][3072] bf16
  u16* vt = qkv + (size_t)T_SEQ * QKV_N;  // [4][128][4096] bf16

  // 1) qkv = hidden @ w_qkv^T  (f32 in, bf16 out)
  gemm_bt<1, 1, 0><<<dim3(QKV_N / 128, T_SEQ / 128), 256, 0, stream>>>(
      hidden, HID, w_qkv, HID, qkv, QKV_N, HID);
  // 2) RoPE + RMSNorm in place on q/k regions
  rope_norm<<<T_SEQ, 256, 0, stream>>>(positions, qkv, qnw, knw);
  // 3) v^T for PV MFMA fragment loads
  transpose_v<<<dim3(T_SEQ / 64, NKV), 256, 0, stream>>>(qkv, vt);
  // 4) flash attention, output over q columns of qkv (row stride 3072)
  attn_kernel<<<dim3(T_SEQ / 64, NH), 256, 0, stream>>>(qkv, vt);
  // 5) out = attn @ w_o^T  (bf16 A, f32 B, f32 out)
  gemm_bt<0, 1, 1><<<dim3(HID / 128, T_SEQ / 128), 256, 0, stream>>>(
      qkv, QKV_N, w_o, HID, out, HID, HID);
}

// Round 3
// 448.983 us; speedup vs baseline: 1.8311x; 1.8311x over previous
//
#include <hip/hip_runtime.h>
#include <hip/hip_bf16.h>

#define T_SEQ 4096
#define HID   2048
#define NH    16
#define NKV   4
#define HD    128
#define QKV_N 3072
// (1/sqrt(128)) * log2(e) folded into q at rope_norm time; attention uses exp2
#define QSCALE 0.12751744f

typedef unsigned short u16;
typedef __bf16 bf16x8 __attribute__((ext_vector_type(8)));
typedef float floatx4 __attribute__((ext_vector_type(4)));
typedef float floatx16 __attribute__((ext_vector_type(16)));

__device__ __forceinline__ float b2f(u16 u) {
  union { unsigned int i; float f; } x; x.i = ((unsigned int)u) << 16; return x.f;
}
__device__ __forceinline__ u16 f2b(float f) {
  union { float f; unsigned int i; } x; x.f = f;
  unsigned int i = x.i;
  unsigned int r = (i + 0x7FFFu + ((i >> 16) & 1u)) >> 16;
  return (u16)r;
}
__device__ __forceinline__ void gload_lds16(const u16* g, u16* lds) {
  __builtin_amdgcn_global_load_lds(
      (const __attribute__((address_space(1))) unsigned int*)g,
      (__attribute__((address_space(3))) unsigned int*)lds, 16, 0, 0);
}

// ---------------- f32 -> bf16 bulk convert ----------------
__global__ __launch_bounds__(256) void conv_f32_bf16(const float* __restrict__ src,
                                                     u16* __restrict__ dst, int n8) {
  int i = blockIdx.x * 256 + threadIdx.x;
  if (i >= n8) return;
  const float4* s = (const float4*)(src + (size_t)i * 8);
  float4 a = s[0], b = s[1];
  union { u16 h[8]; uint4 u; } r;
  r.h[0] = f2b(a.x); r.h[1] = f2b(a.y); r.h[2] = f2b(a.z); r.h[3] = f2b(a.w);
  r.h[4] = f2b(b.x); r.h[5] = f2b(b.y); r.h[6] = f2b(b.z); r.h[7] = f2b(b.w);
  *(uint4*)(dst + (size_t)i * 8) = r.u;
}

// ---------------- bf16 GEMM: C[M,N] = A[M,K]*B[N,K]^T ----------------
// CF=1 -> store f32, else bf16. 128x128 tile, BK=32, global_load_lds staging.
template <int CF>
__global__ __launch_bounds__(256) void gemm_bt(const u16* __restrict__ A, int lda,
                                               const u16* __restrict__ B, int ldb,
                                               void* __restrict__ Cv, int ldc, int K) {
  __shared__ __align__(16) u16 sA[128 * 32];
  __shared__ __align__(16) u16 sB[128 * 32];
  const int tid = threadIdx.x;
  const int wave = tid >> 6, lane = tid & 63;
  const int row0 = blockIdx.y * 128, col0 = blockIdx.x * 128;
  const int wm = (wave >> 1) * 64, wn = (wave & 1) * 64;
  const int frow = lane & 15, fk = (lane >> 4) * 8;

  floatx4 acc[4][4];
#pragma unroll
  for (int i = 0; i < 4; i++)
#pragma unroll
    for (int j = 0; j < 4; j++) acc[i][j] = (floatx4){0.f, 0.f, 0.f, 0.f};

  const int c0 = wave * 2;
  const int v0 = c0 * 64 + lane;
  const int v1 = v0 + 64;
  const u16* gA0 = A + (size_t)(row0 + (v0 >> 2)) * lda + (v0 & 3) * 8;
  const u16* gA1 = A + (size_t)(row0 + (v1 >> 2)) * lda + (v1 & 3) * 8;
  const u16* gB0 = B + (size_t)(col0 + (v0 >> 2)) * ldb + (v0 & 3) * 8;
  const u16* gB1 = B + (size_t)(col0 + (v1 >> 2)) * ldb + (v1 & 3) * 8;

  for (int k0 = 0; k0 < K; k0 += 32) {
    gload_lds16(gA0 + k0, sA + c0 * 512);
    gload_lds16(gA1 + k0, sA + c0 * 512 + 512);
    gload_lds16(gB0 + k0, sB + c0 * 512);
    gload_lds16(gB1 + k0, sB + c0 * 512 + 512);
    __syncthreads();
    bf16x8 af[4], bfv[4];
#pragma unroll
    for (int i = 0; i < 4; i++) {
      af[i]  = *(const bf16x8*)(sA + (wm + i * 16 + frow) * 32 + fk);
      bfv[i] = *(const bf16x8*)(sB + (wn + i * 16 + frow) * 32 + fk);
    }
#pragma unroll
    for (int i = 0; i < 4; i++)
#pragma unroll
      for (int j = 0; j < 4; j++)
        acc[i][j] = __builtin_amdgcn_mfma_f32_16x16x32_bf16(af[i], bfv[j], acc[i][j], 0, 0, 0);
    __syncthreads();
  }
  const int crow = (lane >> 4) * 4, ccol = lane & 15;
#pragma unroll
  for (int i = 0; i < 4; i++)
#pragma unroll
    for (int j = 0; j < 4; j++)
#pragma unroll
      for (int r = 0; r < 4; r++) {
        int rr = row0 + wm + i * 16 + crow + r;
        int cc = col0 + wn + j * 16 + ccol;
        if (CF) ((float*)Cv)[(size_t)rr * ldc + cc] = acc[i][j][r];
        else    ((u16*)Cv)[(size_t)rr * ldc + cc] = f2b(acc[i][j][r]);
      }
}

// ---------------- RoPE + RMSNorm (q scaled by QSCALE) ----------------
__global__ __launch_bounds__(256) void rope_norm(const int* __restrict__ pos_arr,
                                                 u16* __restrict__ qkv,
                                                 const float* __restrict__ qnw,
                                                 const float* __restrict__ knw) {
  const int t = blockIdx.x;
  const int tid = threadIdx.x;
  const int lane = tid & 63, wave = tid >> 6;
  u16* row = qkv + (size_t)t * QKV_N;
  const float pos = (float)pos_arr[t];

  float qv[8];
  float ssq = 0.f;
#pragma unroll
  for (int i = 0; i < 8; i++) {
    int e = tid * 8 + i;
    int r = e & 127, ih = e & 63;
    float invf = __expf(-(float)ih * 0.14391156831212787f); // ln(10000)/64
    float ang = pos * invf;
    float s, c;
    sincosf(ang, &s, &c);
    float val;
    if (r < 64) val = b2f(row[e]) * c - b2f(row[e + 64]) * s;
    else        val = b2f(row[e]) * c + b2f(row[e - 64]) * s;
    qv[i] = val;
    ssq += val * val;
  }
  float kv[2];
  float ssk = 0.f;
  const u16* krow = row + HID;
#pragma unroll
  for (int i = 0; i < 2; i++) {
    int e = tid * 2 + i;
    int r = e & 127, ih = e & 63;
    float invf = __expf(-(float)ih * 0.14391156831212787f);
    float ang = pos * invf;
    float s, c;
    sincosf(ang, &s, &c);
    float val;
    if (r < 64) val = b2f(krow[e]) * c - b2f(krow[e + 64]) * s;
    else        val = b2f(krow[e]) * c + b2f(krow[e - 64]) * s;
    kv[i] = val;
    ssk += val * val;
  }
#pragma unroll
  for (int off = 1; off < 64; off <<= 1) {
    ssq += __shfl_xor(ssq, off);
    ssk += __shfl_xor(ssk, off);
  }
  __shared__ float rq[4], rk[4];
  if (lane == 0) { rq[wave] = ssq; rk[wave] = ssk; }
  __syncthreads();  // also orders all in-place reads before writes below
  float sq = rq[0] + rq[1] + rq[2] + rq[3];
  float sk = rk[0] + rk[1] + rk[2] + rk[3];
  float qsc = rsqrtf(sq * (1.0f / 2048.0f) + 1e-5f) * QSCALE;
  float ksc = rsqrtf(sk * (1.0f / 512.0f) + 1e-5f);
#pragma unroll
  for (int i = 0; i < 8; i++) {
    int e = tid * 8 + i;
    row[e] = f2b(qv[i] * qsc * qnw[e]);
  }
#pragma unroll
  for (int i = 0; i < 2; i++) {
    int e = tid * 2 + i;
    row[HID + e] = f2b(kv[i] * ksc * knw[e]);
  }
}

// ---------------- V transpose: vt[kvh][d][t] ----------------
__global__ __launch_bounds__(256) void transpose_v(const u16* __restrict__ qkv,
                                                   u16* __restrict__ vt) {
  __shared__ __align__(16) u16 tile[64][136];
  const int tid = threadIdx.x;
  const int h = blockIdx.y;
  const int t0 = blockIdx.x * 64;
#pragma unroll
  for (int p = 0; p < 4; p++) {
    int v = p * 256 + tid;
    int r = v >> 4, c = v & 15;
    const u16* g = qkv + (size_t)(t0 + r) * QKV_N + (HID + NKV * HD) + h * HD + c * 8;
    *(uint4*)(&tile[r][c * 8]) = *(const uint4*)g;
  }
  __syncthreads();
#pragma unroll
  for (int p = 0; p < 4; p++) {
    int v = p * 256 + tid;
    int d = v >> 3, c8 = v & 7;
    union { u16 s[8]; uint4 q; } tmp;
#pragma unroll
    for (int i = 0; i < 8; i++) tmp.s[i] = tile[c8 * 8 + i][d];
    u16* g = vt + ((size_t)h * HD + d) * T_SEQ + t0 + c8 * 8;
    *(uint4*)g = tmp.q;
  }
}

// ---------------- Flash attention v2 ----------------
// 256 blocks; block = (head, qt-pair). 4 waves x 32 q rows, q-tile 128, BKV=64.
// S^T = K*Q^T via 32x32x16 MFMA (lane owns one q col -> 1-shfl softmax),
// O^T = V^T*P via 32x32x16. K/V LDS xor-swizzled, double-buffered staging.
__device__ __forceinline__ void stage_kv(const u16* __restrict__ kbase,
                                         const u16* __restrict__ vbase, int kv0,
                                         u16* sk, u16* sv, int tid) {
  const int w = tid >> 6, lane = tid & 63;
#pragma unroll
  for (int i = 0; i < 4; i++) {
    int c = w * 256 + i * 64 + lane;
    int kv = c >> 4, ch = c & 15;
    const u16* g = kbase + (size_t)(kv0 + kv) * QKV_N + ((ch ^ (kv & 7)) * 8);
    gload_lds16(g, sk + (size_t)(w * 256 + i * 64) * 8);
  }
#pragma unroll
  for (int i = 0; i < 4; i++) {
    int c = w * 256 + i * 64 + lane;
    int d = c >> 3, c2 = c & 7;
    const u16* g = vbase + (size_t)d * T_SEQ + kv0 + ((c2 ^ (d & 7)) * 8);
    gload_lds16(g, sv + (size_t)(w * 256 + i * 64) * 8);
  }
}

__global__ __launch_bounds__(256, 2) void attn_kernel(u16* __restrict__ qkv,
                                                      const u16* __restrict__ vt) {
  __shared__ __align__(16) u16 sK[2][64 * 128];  // [kv][d-chunk swizzled]
  __shared__ __align__(16) u16 sV[2][128 * 64];  // [d][kv-chunk swizzled]
  __shared__ __align__(16) u16 sP[4][32 * 64];   // per-wave [q][kv-chunk swizzled]
  const int tid = threadIdx.x;
  const int wave = tid >> 6, lane = tid & 63;
  const int bid = blockIdx.x;
  // decode: 2 XCD slots per kv-head group for L2 residency of K/V
  const int xcd = bid & 7;
  const int kvh = xcd >> 1;
  const int u = ((bid >> 3) << 1) | (xcd & 1);
  const int hsub = u & 3;
  const int pair = u >> 2;                 // 0..15
  const int h = kvh * 4 + hsub;
  const int ql = lane & 31;
  const int fq2 = lane >> 5;
  const u16* kbase = qkv + HID + (size_t)kvh * HD;
  const u16* vbase = vt + (size_t)kvh * HD * T_SEQ;
  u16* sPw = sP[wave];

#pragma unroll 1
  for (int phase = 0; phase < 2; phase++) {
    const int qt = phase ? (31 - pair) : pair;
    const int qb = qt * 128;
    const int qw = qb + wave * 32;
    const int qmax = qw + 31;
    const int qrow = qw + ql;
    // Q B-fragments (8 k-chunks of 16 d)
    bf16x8 qf[8];
    const u16* qp = qkv + (size_t)qrow * QKV_N + h * HD + fq2 * 8;
#pragma unroll
    for (int kc = 0; kc < 8; kc++) qf[kc] = *(const bf16x8*)(qp + kc * 16);
    floatx16 O[4];
#pragma unroll
    for (int dt = 0; dt < 4; dt++)
#pragma unroll
      for (int r = 0; r < 16; r++) O[dt][r] = 0.f;
    float m_run = -1e30f, l_run = 0.f;

    const int nst = 2 * (qt + 1);
    stage_kv(kbase, vbase, 0, sK[0], sV[0], tid);
#pragma unroll 1
    for (int s = 0; s < nst; s++) {
      __syncthreads();  // staged buf[s&1] visible; prefetch from s-1 drained
      if (s + 1 < nst)
        stage_kv(kbase, vbase, (s + 1) * 64, sK[(s + 1) & 1], sV[(s + 1) & 1], tid);
      const int kv0 = s * 64;
      if (kv0 <= qmax) {
        const u16* sk = sK[s & 1];
        const u16* sv = sV[s & 1];
        const int ntv = (kv0 + 32 <= qmax) ? 2 : 1;
        float sc[2][16];
        float mloc = -1e30f;
#pragma unroll
        for (int nt = 0; nt < 2; nt++) {
          if (nt < ntv) {
            floatx16 S;
#pragma unroll
            for (int r = 0; r < 16; r++) S[r] = 0.f;
#pragma unroll
            for (int kc = 0; kc < 8; kc++) {
              int ch = (kc * 2 + fq2) ^ (ql & 7);
              bf16x8 kf = *(const bf16x8*)(sk + ((nt * 32 + ql) * 16 + ch) * 8);
              S = __builtin_amdgcn_mfma_f32_32x32x16_bf16(kf, qf[kc], S, 0, 0, 0);
            }
            const bool tmask = (kv0 + nt * 32 + 31) > qw;
#pragma unroll
            for (int r = 0; r < 16; r++) {
              float v = S[r];
              if (tmask) {
                int kvg = kv0 + nt * 32 + (r & 3) + ((r >> 2) << 3) + (fq2 << 2);
                v = (kvg > qrow) ? -1e30f : v;
              }
              sc[nt][r] = v;
              mloc = fmaxf(mloc, v);
            }
          }
        }
        mloc = fmaxf(mloc, __shfl_xor(mloc, 32));
        float mnew = fmaxf(m_run, mloc);
        float alpha = exp2f(m_run - mnew);
        m_run = mnew;
        float psum = 0.f;
#pragma unroll
        for (int nt = 0; nt < 2; nt++) {
          if (nt < ntv) {
#pragma unroll
            for (int r = 0; r < 16; r++) {
              float p = exp2f(sc[nt][r] - mnew);
              sc[nt][r] = p;
              psum += p;
            }
#pragma unroll
            for (int rg = 0; rg < 4; rg++) {
              int c8 = nt * 8 + rg * 2 + fq2;
              int p8 = c8 ^ ((ql & 7) << 1);
              union { u16 hh[4]; uint2 uu; } wv;
#pragma unroll
              for (int rr = 0; rr < 4; rr++) wv.hh[rr] = f2b(sc[nt][rg * 4 + rr]);
              *(uint2*)(sPw + ql * 64 + p8 * 4) = wv.uu;
            }
          }
        }
        psum += __shfl_xor(psum, 32);
        l_run = l_run * alpha + psum;
#pragma unroll
        for (int dt = 0; dt < 4; dt++)
#pragma unroll
          for (int r = 0; r < 16; r++) O[dt][r] *= alpha;
        asm volatile("s_waitcnt lgkmcnt(0)" ::: "memory");  // sP write->read, same wave
        const int nc2 = min(4, ((qmax - kv0) >> 4) + 1);
#pragma unroll 1
        for (int kc2 = 0; kc2 < nc2; kc2++) {
          int c8 = (kc2 * 2 + fq2) * 2;
          int p8 = c8 ^ ((ql & 7) << 1);
          bf16x8 pf = *(const bf16x8*)(sPw + ql * 64 + p8 * 4);
#pragma unroll
          for (int dt = 0; dt < 4; dt++) {
            int ch2 = (kc2 * 2 + fq2) ^ (ql & 7);
            bf16x8 vf = *(const bf16x8*)(sv + ((dt * 32 + ql) * 8 + ch2) * 8);
            O[dt] = __builtin_amdgcn_mfma_f32_32x32x16_bf16(vf, pf, O[dt], 0, 0, 0);
          }
        }
      }
    }
    __syncthreads();  // all compute done before next phase re-stages buf0
    float inv = 1.0f / fmaxf(l_run, 1e-30f);
    u16* orow = qkv + (size_t)qrow * QKV_N + h * HD;
#pragma unroll
    for (int dt = 0; dt < 4; dt++)
#pragma unroll
      for (int rg = 0; rg < 4; rg++) {
        union { u16 hh[4]; uint2 uu; } wv;
#pragma unroll
        for (int rr = 0; rr < 4; rr++) wv.hh[rr] = f2b(O[dt][rg * 4 + rr] * inv);
        *(uint2*)(orow + dt * 32 + rg * 8 + fq2 * 4) = wv.uu;
      }
  }
}

extern "C" void kernel_launch(void* const* d_in, const int* in_sizes, int n_in,
                              void* d_out, int out_size, void* d_ws, size_t ws_size,
                              hipStream_t stream) {
  const int* positions = (const int*)d_in[0];
  const float* hidden = (const float*)d_in[1];
  const float* w_qkv = (const float*)d_in[2];
  const float* w_o = (const float*)d_in[3];
  const float* qnw = (const float*)d_in[4];
  const float* knw = (const float*)d_in[5];
  float* out = (float*)d_out;

  u16* qkv  = (u16*)d_ws;                       // [4096][3072] bf16, 25.2 MB
  u16* bufA = qkv + (size_t)T_SEQ * QKV_N;      // hidden_bf16 (16.8 MB) -> w_o_bf16
  u16* bufB = bufA + (size_t)T_SEQ * HID;       // w_qkv_bf16 (12.6 MB) -> vt (4.2 MB)

  // 0) one-shot f32 -> bf16 converts (lifetimes allow buffer reuse)
  conv_f32_bf16<<<4096, 256, 0, stream>>>(hidden, bufA, T_SEQ * HID / 8);
  conv_f32_bf16<<<3072, 256, 0, stream>>>(w_qkv, bufB, QKV_N * HID / 8);
  // 1) qkv = hidden @ w_qkv^T (bf16 out)
  gemm_bt<0><<<dim3(QKV_N / 128, T_SEQ / 128), 256, 0, stream>>>(
      bufA, HID, bufB, HID, qkv, QKV_N, HID);
  // 2) RoPE + RMSNorm in place (q pre-scaled by 1/sqrt(D)*log2e)
  rope_norm<<<T_SEQ, 256, 0, stream>>>(positions, qkv, qnw, knw);
  // 3) w_o convert (overwrites hidden_bf16) + v^T (overwrites w_qkv_bf16)
  conv_f32_bf16<<<2048, 256, 0, stream>>>(w_o, bufA, HID * HID / 8);
  transpose_v<<<dim3(T_SEQ / 64, NKV), 256, 0, stream>>>(qkv, bufB);
  // 4) flash attention; output over q columns of qkv
  attn_kernel<<<256, 256, 0, stream>>>(qkv, bufB);
  // 5) out = attn @ w_o^T (f32 out)
  gemm_bt<1><<<dim3(HID / 128, T_SEQ / 128), 256, 0, stream>>>(
      qkv, QKV_N, bufA, HID, out, HID, HID);
}

// Round 4
// 433.050 us; speedup vs baseline: 1.8985x; 1.0368x over previous
//
#include <hip/hip_runtime.h>
#include <hip/hip_bf16.h>

#define T_SEQ 4096
#define HID   2048
#define NH    16
#define NKV   4
#define HD    128
#define QKV_N 3072
// (1/sqrt(128)) * log2(e) folded into q at rope_norm time; attention uses exp2
#define QSCALE 0.12751744f
// static softmax max (log2 units); folded into MFMA accumulator init
#define SMAX 24.0f

typedef unsigned short u16;
typedef __bf16 bf16x8 __attribute__((ext_vector_type(8)));
typedef float floatx4 __attribute__((ext_vector_type(4)));
typedef float floatx16 __attribute__((ext_vector_type(16)));

__device__ __forceinline__ float b2f(u16 u) {
  union { unsigned int i; float f; } x; x.i = ((unsigned int)u) << 16; return x.f;
}
__device__ __forceinline__ u16 f2b(float f) {
  union { float f; unsigned int i; } x; x.f = f;
  unsigned int i = x.i;
  unsigned int r = (i + 0x7FFFu + ((i >> 16) & 1u)) >> 16;
  return (u16)r;
}
__device__ __forceinline__ void gload_lds16(const u16* g, u16* lds) {
  __builtin_amdgcn_global_load_lds(
      (const __attribute__((address_space(1))) unsigned int*)g,
      (__attribute__((address_space(3))) unsigned int*)lds, 16, 0, 0);
}

// ---------------- f32 -> bf16 bulk convert ----------------
__global__ __launch_bounds__(256) void conv_f32_bf16(const float* __restrict__ src,
                                                     u16* __restrict__ dst, int n8) {
  int i = blockIdx.x * 256 + threadIdx.x;
  if (i >= n8) return;
  const float4* s = (const float4*)(src + (size_t)i * 8);
  float4 a = s[0], b = s[1];
  union { u16 h[8]; uint4 u; } r;
  r.h[0] = f2b(a.x); r.h[1] = f2b(a.y); r.h[2] = f2b(a.z); r.h[3] = f2b(a.w);
  r.h[4] = f2b(b.x); r.h[5] = f2b(b.y); r.h[6] = f2b(b.z); r.h[7] = f2b(b.w);
  *(uint4*)(dst + (size_t)i * 8) = r.u;
}

// ---------------- bf16 GEMM: C[M,N] = A[M,K]*B[N,K]^T ----------------
template <int CF>
__global__ __launch_bounds__(256) void gemm_bt(const u16* __restrict__ A, int lda,
                                               const u16* __restrict__ B, int ldb,
                                               void* __restrict__ Cv, int ldc, int K) {
  __shared__ __align__(16) u16 sA[128 * 32];
  __shared__ __align__(16) u16 sB[128 * 32];
  const int tid = threadIdx.x;
  const int wave = tid >> 6, lane = tid & 63;
  const int row0 = blockIdx.y * 128, col0 = blockIdx.x * 128;
  const int wm = (wave >> 1) * 64, wn = (wave & 1) * 64;
  const int frow = lane & 15, fk = (lane >> 4) * 8;

  floatx4 acc[4][4];
#pragma unroll
  for (int i = 0; i < 4; i++)
#pragma unroll
    for (int j = 0; j < 4; j++) acc[i][j] = (floatx4){0.f, 0.f, 0.f, 0.f};

  const int c0 = wave * 2;
  const int v0 = c0 * 64 + lane;
  const int v1 = v0 + 64;
  const u16* gA0 = A + (size_t)(row0 + (v0 >> 2)) * lda + (v0 & 3) * 8;
  const u16* gA1 = A + (size_t)(row0 + (v1 >> 2)) * lda + (v1 & 3) * 8;
  const u16* gB0 = B + (size_t)(col0 + (v0 >> 2)) * ldb + (v0 & 3) * 8;
  const u16* gB1 = B + (size_t)(col0 + (v1 >> 2)) * ldb + (v1 & 3) * 8;

  for (int k0 = 0; k0 < K; k0 += 32) {
    gload_lds16(gA0 + k0, sA + c0 * 512);
    gload_lds16(gA1 + k0, sA + c0 * 512 + 512);
    gload_lds16(gB0 + k0, sB + c0 * 512);
    gload_lds16(gB1 + k0, sB + c0 * 512 + 512);
    __syncthreads();
    bf16x8 af[4], bfv[4];
#pragma unroll
    for (int i = 0; i < 4; i++) {
      af[i]  = *(const bf16x8*)(sA + (wm + i * 16 + frow) * 32 + fk);
      bfv[i] = *(const bf16x8*)(sB + (wn + i * 16 + frow) * 32 + fk);
    }
#pragma unroll
    for (int i = 0; i < 4; i++)
#pragma unroll
      for (int j = 0; j < 4; j++)
        acc[i][j] = __builtin_amdgcn_mfma_f32_16x16x32_bf16(af[i], bfv[j], acc[i][j], 0, 0, 0);
    __syncthreads();
  }
  const int crow = (lane >> 4) * 4, ccol = lane & 15;
#pragma unroll
  for (int i = 0; i < 4; i++)
#pragma unroll
    for (int j = 0; j < 4; j++)
#pragma unroll
      for (int r = 0; r < 4; r++) {
        int rr = row0 + wm + i * 16 + crow + r;
        int cc = col0 + wn + j * 16 + ccol;
        if (CF) ((float*)Cv)[(size_t)rr * ldc + cc] = acc[i][j][r];
        else    ((u16*)Cv)[(size_t)rr * ldc + cc] = f2b(acc[i][j][r]);
      }
}

// ---------------- RoPE + RMSNorm (q scaled by QSCALE) ----------------
// fast hw sincos: angle -> revolutions -> fract -> v_sin/v_cos.
__device__ __forceinline__ void fast_sincos(float ang, float* s, float* c) {
  float r = ang * 0.15915494309189535f;
  r -= floorf(r);
  *s = __builtin_amdgcn_sinf(r);
  *c = __builtin_amdgcn_cosf(r);
}

__global__ __launch_bounds__(256) void rope_norm(const int* __restrict__ pos_arr,
                                                 u16* __restrict__ qkv,
                                                 const float* __restrict__ qnw,
                                                 const float* __restrict__ knw) {
  const int t = blockIdx.x;
  const int tid = threadIdx.x;
  const int lane = tid & 63, wave = tid >> 6;
  u16* row = qkv + (size_t)t * QKV_N;
  const float pos = (float)pos_arr[t];

  float qv[8];
  float ssq = 0.f;
#pragma unroll
  for (int i = 0; i < 8; i++) {
    int e = tid * 8 + i;
    int r = e & 127, ih = e & 63;
    float invf = exp2f(-(float)ih * 0.20762050593046015f); // log2(10000)/64
    float ang = pos * invf;
    float s, c;
    fast_sincos(ang, &s, &c);
    float val;
    if (r < 64) val = b2f(row[e]) * c - b2f(row[e + 64]) * s;
    else        val = b2f(row[e]) * c + b2f(row[e - 64]) * s;
    qv[i] = val;
    ssq += val * val;
  }
  float kv[2];
  float ssk = 0.f;
  const u16* krow = row + HID;
#pragma unroll
  for (int i = 0; i < 2; i++) {
    int e = tid * 2 + i;
    int r = e & 127, ih = e & 63;
    float invf = exp2f(-(float)ih * 0.20762050593046015f);
    float ang = pos * invf;
    float s, c;
    fast_sincos(ang, &s, &c);
    float val;
    if (r < 64) val = b2f(krow[e]) * c - b2f(krow[e + 64]) * s;
    else        val = b2f(krow[e]) * c + b2f(krow[e - 64]) * s;
    kv[i] = val;
    ssk += val * val;
  }
#pragma unroll
  for (int off = 1; off < 64; off <<= 1) {
    ssq += __shfl_xor(ssq, off);
    ssk += __shfl_xor(ssk, off);
  }
  __shared__ float rq[4], rk[4];
  if (lane == 0) { rq[wave] = ssq; rk[wave] = ssk; }
  __syncthreads();  // also orders all in-place reads before writes below
  float sq = rq[0] + rq[1] + rq[2] + rq[3];
  float sk = rk[0] + rk[1] + rk[2] + rk[3];
  float qsc = rsqrtf(sq * (1.0f / 2048.0f) + 1e-5f) * QSCALE;
  float ksc = rsqrtf(sk * (1.0f / 512.0f) + 1e-5f);
#pragma unroll
  for (int i = 0; i < 8; i++) {
    int e = tid * 8 + i;
    row[e] = f2b(qv[i] * qsc * qnw[e]);
  }
#pragma unroll
  for (int i = 0; i < 2; i++) {
    int e = tid * 2 + i;
    row[HID + e] = f2b(kv[i] * ksc * knw[e]);
  }
}

// ---------------- V transpose: vt[kvh][d][t] ----------------
__global__ __launch_bounds__(256) void transpose_v(const u16* __restrict__ qkv,
                                                   u16* __restrict__ vt) {
  __shared__ __align__(16) u16 tile[64][136];
  const int tid = threadIdx.x;
  const int h = blockIdx.y;
  const int t0 = blockIdx.x * 64;
#pragma unroll
  for (int p = 0; p < 4; p++) {
    int v = p * 256 + tid;
    int r = v >> 4, c = v & 15;
    const u16* g = qkv + (size_t)(t0 + r) * QKV_N + (HID + NKV * HD) + h * HD + c * 8;
    *(uint4*)(&tile[r][c * 8]) = *(const uint4*)g;
  }
  __syncthreads();
#pragma unroll
  for (int p = 0; p < 4; p++) {
    int v = p * 256 + tid;
    int d = v >> 3, c8 = v & 7;
    union { u16 s[8]; uint4 q; } tmp;
#pragma unroll
    for (int i = 0; i < 8; i++) tmp.s[i] = tile[c8 * 8 + i][d];
    u16* g = vt + ((size_t)h * HD + d) * T_SEQ + t0 + c8 * 8;
    *(uint4*)g = tmp.q;
  }
}

// ---------------- Flash attention v3 ----------------
// 512 blocks, one (head, qt) each; (c, c+256) CU-pairing balances load.
// Static-max softmax: S accumulator init = -SMAX, p = exp2(s) directly;
// no running max / rescale / per-step shfl. l = per-lane sum + 1 final shfl.
__device__ __forceinline__ void stage_kv(const u16* __restrict__ kbase,
                                         const u16* __restrict__ vbase, int kv0,
                                         u16* sk, u16* sv, int tid) {
  const int w = tid >> 6, lane = tid & 63;
#pragma unroll
  for (int i = 0; i < 4; i++) {
    int c = w * 256 + i * 64 + lane;
    int kv = c >> 4, ch = c & 15;
    const u16* g = kbase + (size_t)(kv0 + kv) * QKV_N + ((ch ^ (kv & 7)) * 8);
    gload_lds16(g, sk + (size_t)(w * 256 + i * 64) * 8);
  }
#pragma unroll
  for (int i = 0; i < 4; i++) {
    int c = w * 256 + i * 64 + lane;
    int d = c >> 3, c2 = c & 7;
    const u16* g = vbase + (size_t)d * T_SEQ + kv0 + ((c2 ^ (d & 7)) * 8);
    gload_lds16(g, sv + (size_t)(w * 256 + i * 64) * 8);
  }
}

__global__ __launch_bounds__(256, 2) void attn_kernel(u16* __restrict__ qkv,
                                                      const u16* __restrict__ vt) {
  __shared__ __align__(16) u16 sK[2][64 * 128];  // [kv][d-chunk swizzled]
  __shared__ __align__(16) u16 sV[2][128 * 64];  // [d][kv-chunk swizzled]
  __shared__ __align__(16) u16 sP[4][32 * 64];   // per-wave [q][kv-chunk swizzled]
  const int tid = threadIdx.x;
  const int wave = tid >> 6, lane = tid & 63;
  const int bid = blockIdx.x;
  // (c, c+256) pairing: qt(c)+qt(c+256)=31 -> 66 kv-steps per CU; one head
  // per XCD slot for K/V L2 residency.
  int qt, h;
  if (bid < 256) { qt = bid >> 3; h = bid & 7; }
  else           { qt = 31 - ((bid & 255) >> 3); h = 8 + (bid & 7); }
  const int kvh = h >> 2;
  const int ql = lane & 31;
  const int fq2 = lane >> 5;
  const u16* kbase = qkv + HID + (size_t)kvh * HD;
  const u16* vbase = vt + (size_t)kvh * HD * T_SEQ;
  u16* sPw = sP[wave];

  const int qb = qt * 128;
  const int qw = qb + wave * 32;
  const int qmax = qw + 31;
  const int qrow = qw + ql;
  // Q B-fragments (8 k-chunks of 16 d)
  bf16x8 qf[8];
  const u16* qp = qkv + (size_t)qrow * QKV_N + h * HD + fq2 * 8;
#pragma unroll
  for (int kc = 0; kc < 8; kc++) qf[kc] = *(const bf16x8*)(qp + kc * 16);
  floatx16 O[4];
#pragma unroll
  for (int dt = 0; dt < 4; dt++)
#pragma unroll
    for (int r = 0; r < 16; r++) O[dt][r] = 0.f;
  float l_part = 0.f;

  const int nst = 2 * (qt + 1);
  stage_kv(kbase, vbase, 0, sK[0], sV[0], tid);
#pragma unroll 1
  for (int s = 0; s < nst; s++) {
    __syncthreads();  // staged buf[s&1] visible; prefetch from s-1 drained
    if (s + 1 < nst)
      stage_kv(kbase, vbase, (s + 1) * 64, sK[(s + 1) & 1], sV[(s + 1) & 1], tid);
    const int kv0 = s * 64;
    if (kv0 <= qmax) {
      const u16* sk = sK[s & 1];
      const u16* sv = sV[s & 1];
      const int ntv = (kv0 + 32 <= qmax) ? 2 : 1;
#pragma unroll
      for (int nt = 0; nt < 2; nt++) {
        if (nt < ntv) {
          floatx16 S;
#pragma unroll
          for (int r = 0; r < 16; r++) S[r] = -SMAX;
#pragma unroll
          for (int kc = 0; kc < 8; kc++) {
            int ch = (kc * 2 + fq2) ^ (ql & 7);
            bf16x8 kf = *(const bf16x8*)(sk + ((nt * 32 + ql) * 16 + ch) * 8);
            S = __builtin_amdgcn_mfma_f32_32x32x16_bf16(kf, qf[kc], S, 0, 0, 0);
          }
          const bool tmask = (kv0 + nt * 32 + 31) > qw;
#pragma unroll
          for (int r = 0; r < 16; r++) {
            float v = S[r];
            if (tmask) {
              int kvg = kv0 + nt * 32 + (r & 3) + ((r >> 2) << 3) + (fq2 << 2);
              v = (kvg > qrow) ? -1e30f : v;
            }
            float p = exp2f(v);
            l_part += p;
            S[r] = p;
          }
          // pack P (truncation) via v_perm: {hi16(even), hi16(odd)}
#pragma unroll
          for (int rg = 0; rg < 4; rg++) {
            int c8 = nt * 8 + rg * 2 + fq2;
            int p8 = c8 ^ ((ql & 7) << 1);
            unsigned lo = __builtin_amdgcn_perm(__float_as_uint(S[rg * 4 + 1]),
                                                __float_as_uint(S[rg * 4 + 0]),
                                                0x07060302u);
            unsigned hi = __builtin_amdgcn_perm(__float_as_uint(S[rg * 4 + 3]),
                                                __float_as_uint(S[rg * 4 + 2]),
                                                0x07060302u);
            uint2 wv = {lo, hi};
            *(uint2*)(sPw + ql * 64 + p8 * 4) = wv;
          }
        }
      }
      asm volatile("s_waitcnt lgkmcnt(0)" ::: "memory");  // sP write->read, same wave
      const int nc2 = min(4, ((qmax - kv0) >> 4) + 1);
#pragma unroll 1
      for (int kc2 = 0; kc2 < nc2; kc2++) {
        int c8 = (kc2 * 2 + fq2) * 2;
        int p8 = c8 ^ ((ql & 7) << 1);
        bf16x8 pf = *(const bf16x8*)(sPw + ql * 64 + p8 * 4);
#pragma unroll
        for (int dt = 0; dt < 4; dt++) {
          int ch2 = (kc2 * 2 + fq2) ^ (ql & 7);
          bf16x8 vf = *(const bf16x8*)(sv + ((dt * 32 + ql) * 8 + ch2) * 8);
          O[dt] = __builtin_amdgcn_mfma_f32_32x32x16_bf16(vf, pf, O[dt], 0, 0, 0);
        }
      }
    }
  }
  float l = l_part + __shfl_xor(l_part, 32);
  float inv = 1.0f / fmaxf(l, 1e-30f);
  u16* orow = qkv + (size_t)qrow * QKV_N + h * HD;
#pragma unroll
  for (int dt = 0; dt < 4; dt++)
#pragma unroll
    for (int rg = 0; rg < 4; rg++) {
      union { u16 hh[4]; uint2 uu; } wv;
#pragma unroll
      for (int rr = 0; rr < 4; rr++) wv.hh[rr] = f2b(O[dt][rg * 4 + rr] * inv);
      *(uint2*)(orow + dt * 32 + rg * 8 + fq2 * 4) = wv.uu;
    }
}

extern "C" void kernel_launch(void* const* d_in, const int* in_sizes, int n_in,
                              void* d_out, int out_size, void* d_ws, size_t ws_size,
                              hipStream_t stream) {
  const int* positions = (const int*)d_in[0];
  const float* hidden = (const float*)d_in[1];
  const float* w_qkv = (const float*)d_in[2];
  const float* w_o = (const float*)d_in[3];
  const float* qnw = (const float*)d_in[4];
  const float* knw = (const float*)d_in[5];
  float* out = (float*)d_out;

  u16* qkv  = (u16*)d_ws;                       // [4096][3072] bf16, 25.2 MB
  u16* bufA = qkv + (size_t)T_SEQ * QKV_N;      // hidden_bf16 (16.8 MB) -> w_o_bf16
  u16* bufB = bufA + (size_t)T_SEQ * HID;       // w_qkv_bf16 (12.6 MB) -> vt (4.2 MB)

  // 0) one-shot f32 -> bf16 converts (lifetimes allow buffer reuse)
  conv_f32_bf16<<<4096, 256, 0, stream>>>(hidden, bufA, T_SEQ * HID / 8);
  conv_f32_bf16<<<3072, 256, 0, stream>>>(w_qkv, bufB, QKV_N * HID / 8);
  // 1) qkv = hidden @ w_qkv^T (bf16 out)
  gemm_bt<0><<<dim3(QKV_N / 128, T_SEQ / 128), 256, 0, stream>>>(
      bufA, HID, bufB, HID, qkv, QKV_N, HID);
  // 2) RoPE + RMSNorm in place (q pre-scaled by 1/sqrt(D)*log2e)
  rope_norm<<<T_SEQ, 256, 0, stream>>>(positions, qkv, qnw, knw);
  // 3) w_o convert (overwrites hidden_bf16) + v^T (overwrites w_qkv_bf16)
  conv_f32_bf16<<<2048, 256, 0, stream>>>(w_o, bufA, HID * HID / 8);
  transpose_v<<<dim3(T_SEQ / 64, NKV), 256, 0, stream>>>(qkv, bufB);
  // 4) flash attention; output over q columns of qkv
  attn_kernel<<<512, 256, 0, stream>>>(qkv, bufB);
  // 5) out = attn @ w_o^T (f32 out)
  gemm_bt<1><<<dim3(HID / 128, T_SEQ / 128), 256, 0, stream>>>(
      qkv, QKV_N, bufA, HID, out, HID, HID);
}